// Round 15
// baseline (1140.397 us; speedup 1.0000x reference)
//
#include <hip/hip_runtime.h>
#include <cstdint>
#include <cstddef>

#define NN 50000
#define EE 300000
#define HH 64
#define PP 3
#define GG 50
#define LL 2
#define CAP 32
#define SLOPE 0.01f

typedef __attribute__((ext_vector_type(8))) short bf16x8;
typedef __attribute__((ext_vector_type(4))) float f32x4;

__device__ __forceinline__ float lrelu(float x){ return x >= 0.f ? x : SLOPE*x; }

__device__ __forceinline__ unsigned short f2bf(float x){
    uint32_t u = __float_as_uint(x);
    uint32_t r = (u + 0x7FFFu + ((u >> 16) & 1u)) >> 16;
    return (unsigned short)r;
}
__device__ __forceinline__ float bf2f(unsigned short s){
    return __uint_as_float((uint32_t)s << 16);
}

// gstart[g] = first index i with batch[i] >= g (batch sorted); gstart[GG] = NN
__global__ void k_bounds(const int* __restrict__ batch, int* __restrict__ gstart){
    int g = threadIdx.x;
    if (g > GG) return;
    int lo = 0, hi = NN;
    while (lo < hi){ int mid = (lo + hi) >> 1; if (batch[mid] < g) lo = mid + 1; else hi = mid; }
    gstart[g] = lo;
}

// pe4[n] = {pe[n][0], pe[n][1], pe[n][2], 0}
__global__ void k_pe4(const float* __restrict__ pe, float4* __restrict__ pe4){
    int n = blockIdx.x * blockDim.x + threadIdx.x;
    if (n >= NN) return;
    pe4[n] = make_float4(pe[n * 3 + 0], pe[n * 3 + 1], pe[n * 3 + 2], 0.f);
}

// Single-pass bucket-CSR fill over all 6 edge sets.
__global__ void k_fill2(const int* __restrict__ uei, const float* __restrict__ uew,
                        const int* __restrict__ fei, const float* __restrict__ few,
                        int* __restrict__ cnt, int2* __restrict__ bucket){
    int t = blockIdx.x * blockDim.x + threadIdx.x;
    if (t >= 2 * PP * EE) return;
    int which = t / EE;
    int e = t - which * EE;
    const int* ei; const float* ew; int p;
    if (which < PP){ ei = uei; ew = uew; p = which; }
    else           { ei = fei; ew = few; p = which - PP; }
    int row = ei[(size_t)(p * 2 + 0) * EE + e];
    int col = ei[(size_t)(p * 2 + 1) * EE + e];
    float w = ew[(size_t)p * EE + e];
    int slot = atomicAdd(cnt + (size_t)which * NN + row, 1);
    if (slot < CAP)
        bucket[((size_t)which * NN + row) * CAP + slot] = make_int2(col, __float_as_int(w));
}

// Pre-pack ALL 12 fusion weight matrices into bf16 B-fragment order:
// Wpb[t][kb][w][lane][j] = bf16( src[kref(kb*32 + (lane>>4)*8 + j)][w*16 + (lane&15)] )
__global__ void k_wpermb(const float* __restrict__ S_fW, const float* __restrict__ F_fW,
                         unsigned short* __restrict__ Wpb){
    int gid = blockIdx.x * blockDim.x + threadIdx.x;   // 12*16*4*64*8 = 393216
    int j = gid & 7;
    int lane = (gid >> 3) & 63;
    int w = (gid >> 9) & 3;
    int kb = (gid >> 11) & 15;
    int t = gid >> 15;
    int q = kb * 32 + (lane >> 4) * 8 + j;
    int col = w * 16 + (lane & 15);
    int conv = t / 6, layer = (t % 6) / 3, p = t % 3;
    const float* src = (conv ? F_fW : S_fW) + ((size_t)layer * PP + p) * 512 * HH;
    int kref;
    if (q < 128) kref = q;
    else { int r = q - 128; kref = 128 + (r & 63) * 6 + (r >> 6); }
    Wpb[gid] = f2bf(src[(size_t)kref * HH + col]);
}

// Register-blocked (N,64)@(64,64), fp32 out: 32 nodes/block, 4 waves, 8 nodes/wave.
__global__ __launch_bounds__(256) void k_lin64(const float* __restrict__ X,
                       const float* __restrict__ W, const float* __restrict__ b,
                       float* __restrict__ out){
    __shared__ float xs[32][HH];
    int nb = blockIdx.x * 32;
    int t = threadIdx.x;
    #pragma unroll
    for (int i = 0; i < 2; ++i){
        int idx = t + 256 * i;
        int r = idx >> 4, c4 = idx & 15;
        int n = nb + r;
        float4 v = make_float4(0.f, 0.f, 0.f, 0.f);
        if (n < NN) v = *reinterpret_cast<const float4*>(X + (size_t)n * HH + c4 * 4);
        *reinterpret_cast<float4*>(&xs[r][c4 * 4]) = v;
    }
    __syncthreads();
    int lane = t & 63, wave = t >> 6, nw = wave * 8;
    float acc[8];
    float bb = b[lane];
    #pragma unroll
    for (int i = 0; i < 8; ++i) acc[i] = bb;
    #pragma unroll 2
    for (int k = 0; k < HH; ++k){
        float wv = W[(size_t)k * HH + lane];
        #pragma unroll
        for (int i = 0; i < 8; ++i) acc[i] += xs[nw + i][k] * wv;
    }
    #pragma unroll
    for (int i = 0; i < 8; ++i){
        int n = nb + nw + i;
        if (n < NN) out[(size_t)n * HH + lane] = acc[i];
    }
}

// Same but bf16 output (for the xt buffer consumed by k_hop3).
__global__ __launch_bounds__(256) void k_lin64b(const float* __restrict__ X,
                       const float* __restrict__ W, const float* __restrict__ b,
                       unsigned short* __restrict__ out){
    __shared__ float xs[32][HH];
    int nb = blockIdx.x * 32;
    int t = threadIdx.x;
    #pragma unroll
    for (int i = 0; i < 2; ++i){
        int idx = t + 256 * i;
        int r = idx >> 4, c4 = idx & 15;
        int n = nb + r;
        float4 v = make_float4(0.f, 0.f, 0.f, 0.f);
        if (n < NN) v = *reinterpret_cast<const float4*>(X + (size_t)n * HH + c4 * 4);
        *reinterpret_cast<float4*>(&xs[r][c4 * 4]) = v;
    }
    __syncthreads();
    int lane = t & 63, wave = t >> 6, nw = wave * 8;
    float acc[8];
    float bb = b[lane];
    #pragma unroll
    for (int i = 0; i < 8; ++i) acc[i] = bb;
    #pragma unroll 2
    for (int k = 0; k < HH; ++k){
        float wv = W[(size_t)k * HH + lane];
        #pragma unroll
        for (int i = 0; i < 8; ++i) acc[i] += xs[nw + i][k] * wv;
    }
    #pragma unroll
    for (int i = 0; i < 8; ++i){
        int n = nb + nw + i;
        if (n < NN) out[(size_t)n * HH + lane] = f2bf(acc[i]);
    }
}

// Whole OPDMP (3 hops), MFMA phase B, bf16 xt gathers.
// Phase A uses the relu identity: accumulate s_k = sum dd_k*xv, t_k = sum |dd_k|*xv;
// dir_pos = (t+s)/2, dir_neg = (t-s)/2.  |dd| is a free VOP3 input modifier.
__global__ __launch_bounds__(256) void k_hop3(const unsigned short* __restrict__ xtb,
        const int* __restrict__ cnt, const int2* __restrict__ bucket,
        const float4* __restrict__ pe4, const unsigned short* __restrict__ Wpb3,
        const float* __restrict__ fb3, const float* __restrict__ dmat,
        const float* __restrict__ hb3, float* __restrict__ outb){
    __shared__ unsigned short u[16][512];
    int nb = blockIdx.x * 16;
    int t = threadIdx.x;
    int lane = t & 63, wave = t >> 6, nw = wave * 4;
    // stage bf16 xt rows into u[.][0:64] (swizzled); 8B per thread
    {
        int r = t >> 4, c4 = t & 15;
        ushort4 s = *reinterpret_cast<const ushort4*>(xtb + (size_t)(nb + r) * HH + c4 * 4);
        int q = (c4 * 4) ^ ((r & 7) << 3);
        *reinterpret_cast<ushort4*>(&u[r][q]) = s;
    }
    int c = wave * 16 + (lane & 15);
    float d0 = dmat[c], d1 = dmat[64 + c], d2 = dmat[128 + c];
    float mx = fmaxf(d0, fmaxf(d1, d2));
    float e0 = expf(d0 - mx), e1 = expf(d1 - mx), e2 = expf(d2 - mx);
    float esum = e0 + e1 + e2;
    float dw0 = e0 / esum, dw1 = e1 / esum, dw2 = e2 / esum;
    float accOut[4];
    float hbs = hb3[c] + hb3[64 + c] + hb3[128 + c];
    #pragma unroll
    for (int r = 0; r < 4; ++r) accOut[r] = hbs;

    for (int p = 0; p < 3; ++p){
        __syncthreads();
        const int*  cntp = cnt + (size_t)p * NN;
        const int2* bp   = bucket + (size_t)p * NN * CAP;
        #pragma unroll
        for (int i = 0; i < 4; ++i){
            int n = nb + nw + i;
            float accA = 0.f, sumw = 0.f;
            float s0 = 0.f, s1 = 0.f, s2 = 0.f, t0 = 0.f, t1 = 0.f, t2 = 0.f;
            int len = cntp[n]; if (len > CAP) len = CAP;
            const int2* b = bp + (size_t)n * CAP;
            float4 pr = pe4[n];
            {   // predicated batch covering s=0..7
                int  cols[8]; float ws[8];
                #pragma unroll
                for (int s = 0; s < 8; ++s){
                    int2 m = b[s];
                    bool ok = (s < len);
                    cols[s] = ok ? m.x : n;
                    ws[s]   = ok ? __int_as_float(m.y) : 0.f;
                }
                float4 pcs[8]; float xvs[8];
                #pragma unroll
                for (int s = 0; s < 8; ++s){
                    pcs[s] = pe4[cols[s]];
                    xvs[s] = bf2f(xtb[(size_t)cols[s] * HH + lane]);
                }
                #pragma unroll
                for (int s = 0; s < 8; ++s){
                    float w = ws[s], xv = xvs[s];
                    float dd0 = pcs[s].x - pr.x;
                    float dd1 = pcs[s].y - pr.y;
                    float dd2 = pcs[s].z - pr.z;
                    sumw += w;  accA += w * xv;
                    s0 += dd0 * xv;  t0 += fabsf(dd0) * xv;
                    s1 += dd1 * xv;  t1 += fabsf(dd1) * xv;
                    s2 += dd2 * xv;  t2 += fabsf(dd2) * xv;
                }
            }
            if (len > 8){   // predicated batch covering s=8..15
                int  cols[8]; float ws[8];
                #pragma unroll
                for (int s = 0; s < 8; ++s){
                    int2 m = b[8 + s];
                    bool ok = (8 + s < len);
                    cols[s] = ok ? m.x : n;
                    ws[s]   = ok ? __int_as_float(m.y) : 0.f;
                }
                float4 pcs[8]; float xvs[8];
                #pragma unroll
                for (int s = 0; s < 8; ++s){
                    pcs[s] = pe4[cols[s]];
                    xvs[s] = bf2f(xtb[(size_t)cols[s] * HH + lane]);
                }
                #pragma unroll
                for (int s = 0; s < 8; ++s){
                    float w = ws[s], xv = xvs[s];
                    float dd0 = pcs[s].x - pr.x;
                    float dd1 = pcs[s].y - pr.y;
                    float dd2 = pcs[s].z - pr.z;
                    sumw += w;  accA += w * xv;
                    s0 += dd0 * xv;  t0 += fabsf(dd0) * xv;
                    s1 += dd1 * xv;  t1 += fabsf(dd1) * xv;
                    s2 += dd2 * xv;  t2 += fabsf(dd2) * xv;
                }
            }
            for (int s = 16; s < len; ++s){      // P(len>16) ~ 2e-4
                int2 m = b[s];
                int col = m.x;
                float w = __int_as_float(m.y);
                float4 pc = pe4[col];
                float xv = bf2f(xtb[(size_t)col * HH + lane]);
                float dd0 = pc.x - pr.x;
                float dd1 = pc.y - pr.y;
                float dd2 = pc.z - pr.z;
                sumw += w;  accA += w * xv;
                s0 += dd0 * xv;  t0 += fabsf(dd0) * xv;
                s1 += dd1 * xv;  t1 += fabsf(dd1) * xv;
                s2 += dd2 * xv;  t2 += fabsf(dd2) * xv;
            }
            float di = (sumw == 0.f) ? 0.f : 1.f / sumw;
            float dh = 0.5f * di;
            int il = nw + i;
            int sw = (il & 7) << 3;
            u[il][(64 + lane) ^ sw]           = f2bf(accA * di);
            u[il][(128 + 0 * 64 + lane) ^ sw] = f2bf((t0 + s0) * dh);
            u[il][(128 + 1 * 64 + lane) ^ sw] = f2bf((t1 + s1) * dh);
            u[il][(128 + 2 * 64 + lane) ^ sw] = f2bf((t2 + s2) * dh);
            u[il][(128 + 3 * 64 + lane) ^ sw] = f2bf((t0 - s0) * dh);
            u[il][(128 + 4 * 64 + lane) ^ sw] = f2bf((t1 - s1) * dh);
            u[il][(128 + 5 * 64 + lane) ^ sw] = f2bf((t2 - s2) * dh);
        }
        __syncthreads();
        // ---- phase B: MFMA GEMM. wave -> col-stripe [wave*16, wave*16+16) ----
        const unsigned short* wb = Wpb3 + (size_t)p * 32768;
        f32x4 acc = {0.f, 0.f, 0.f, 0.f};
        int arow = lane & 15;
        int asw = (arow & 7) << 3;
        #pragma unroll
        for (int kb = 0; kb < 16; ++kb){
            int qa = (kb * 32 + (lane >> 4) * 8) ^ asw;
            bf16x8 a = *reinterpret_cast<const bf16x8*>(&u[arow][qa]);
            bf16x8 b = *reinterpret_cast<const bf16x8*>(&wb[(((size_t)kb * 4 + wave) * 64 + lane) * 8]);
            acc = __builtin_amdgcn_mfma_f32_16x16x32_bf16(a, b, acc, 0, 0, 0);
        }
        float fbv = fb3[p * 64 + c];
        float dw = (p == 0) ? dw0 : ((p == 1) ? dw1 : dw2);
        #pragma unroll
        for (int r = 0; r < 4; ++r)
            accOut[r] += lrelu(acc[r] + fbv) * dw;
    }
    #pragma unroll
    for (int r = 0; r < 4; ++r){
        int row = (lane >> 4) * 4 + r;
        outb[(size_t)(nb + row) * HH + c] = accOut[r];
    }
}

// Per-graph partial sums/sumsq in 4 row-chunks (no atomics, no memset).
__global__ void k_stats4(const float* __restrict__ X, const int* __restrict__ gstart,
                         float* __restrict__ sums4, float* __restrict__ sumsq4){
    int g = blockIdx.x, chunk = blockIdx.y;
    int o = threadIdx.x & 63, sub = threadIdx.x >> 6;
    int ns = gstart[g], ne = gstart[g + 1];
    float s = 0.f, q = 0.f;
    for (int n = ns + chunk * 4 + sub; n < ne; n += 16){
        float v = X[(size_t)n * 64 + o];
        s += v; q += v * v;
    }
    __shared__ float ls[4][64];
    __shared__ float lq[4][64];
    ls[sub][o] = s; lq[sub][o] = q;
    __syncthreads();
    if (sub == 0){
        #pragma unroll
        for (int k = 1; k < 4; ++k){ s += ls[k][o]; q += lq[k][o]; }
        sums4 [(size_t)(chunk * GG + g) * 64 + o] = s;
        sumsq4[(size_t)(chunk * GG + g) * 64 + o] = q;
    }
}

// graph-norm + leaky_relu, in place; reduces the 4 partials inline.
__global__ void k_gnorm(float* __restrict__ X, const int* __restrict__ batch,
                        const int* __restrict__ gstart,
                        const float* __restrict__ sums4, const float* __restrict__ sumsq4,
                        const float* __restrict__ w, const float* __restrict__ b,
                        const float* __restrict__ ms){
    int gid = blockIdx.x * blockDim.x + threadIdx.x;
    if (gid >= NN * HH) return;
    int n = gid >> 6, o = gid & 63;
    int g = batch[n];
    float cnt = fmaxf((float)(gstart[g + 1] - gstart[g]), 1.f);
    float sm = 0.f, sq = 0.f;
    #pragma unroll
    for (int cC = 0; cC < 4; ++cC){
        sm += sums4 [(size_t)(cC * GG + g) * 64 + o];
        sq += sumsq4[(size_t)(cC * GG + g) * 64 + o];
    }
    float mean = sm / cnt;
    float ex2 = sq / cnt;
    float m = ms[o];
    float var = ex2 - mean * mean * m * (2.f - m);
    float v = (X[gid] - mean * m) * (1.f / sqrtf(var + 1e-5f)) * w[o] + b[o];
    X[gid] = lrelu(v);
}

// gate = sigmoid([h,fx] @ gate_W + gate_b); X = gate*h + (1-gate)*fx + X
__global__ __launch_bounds__(256) void k_gate2(const float* __restrict__ h,
                       const float* __restrict__ fx, const float* __restrict__ gW,
                       const float* __restrict__ gb, float* __restrict__ X){
    __shared__ float hs[32][HH];
    __shared__ float fs[32][HH];
    int nb = blockIdx.x * 32;
    int t = threadIdx.x;
    #pragma unroll
    for (int i = 0; i < 2; ++i){
        int idx = t + 256 * i;
        int r = idx >> 4, c4 = idx & 15;
        int n = nb + r;
        float4 vh = make_float4(0.f, 0.f, 0.f, 0.f);
        float4 vf = make_float4(0.f, 0.f, 0.f, 0.f);
        if (n < NN){
            vh = *reinterpret_cast<const float4*>(h  + (size_t)n * HH + c4 * 4);
            vf = *reinterpret_cast<const float4*>(fx + (size_t)n * HH + c4 * 4);
        }
        *reinterpret_cast<float4*>(&hs[r][c4 * 4]) = vh;
        *reinterpret_cast<float4*>(&fs[r][c4 * 4]) = vf;
    }
    __syncthreads();
    int lane = t & 63, wave = t >> 6, nw = wave * 8;
    float acc[8];
    float bb = gb[lane];
    #pragma unroll
    for (int i = 0; i < 8; ++i) acc[i] = bb;
    #pragma unroll 2
    for (int k = 0; k < HH; ++k){
        float w1 = gW[(size_t)k * HH + lane];
        float w2 = gW[(size_t)(64 + k) * HH + lane];
        #pragma unroll
        for (int i = 0; i < 8; ++i) acc[i] += hs[nw + i][k] * w1 + fs[nw + i][k] * w2;
    }
    #pragma unroll
    for (int i = 0; i < 8; ++i){
        int n = nb + nw + i;
        if (n < NN){
            float gt = 1.f / (1.f + expf(-acc[i]));
            float hv = hs[nw + i][lane];
            float fv = fs[nw + i][lane];
            size_t idx = (size_t)n * HH + lane;
            X[idx] = gt * hv + (1.f - gt) * fv + X[idx];
        }
    }
}

__global__ void k_finalout(const float* __restrict__ sums4, const int* __restrict__ gstart,
                           float* __restrict__ out){
    int gid = blockIdx.x * blockDim.x + threadIdx.x;
    if (gid >= GG * HH) return;
    int g = gid >> 6, o = gid & 63;
    float cnt = fmaxf((float)(gstart[g + 1] - gstart[g]), 1.f);
    float sm = 0.f;
    #pragma unroll
    for (int cC = 0; cC < 4; ++cC) sm += sums4[(size_t)(cC * GG + g) * 64 + o];
    out[gid] = sm / cnt;
}

extern "C" void kernel_launch(void* const* d_in, const int* in_sizes, int n_in,
                              void* d_out, int out_size, void* d_ws, size_t ws_size,
                              hipStream_t stream) {
    const float* x_in   = (const float*)d_in[0];
    const float* pe     = (const float*)d_in[1];
    const int*   batch  = (const int*)d_in[2];
    const int*   uei    = (const int*)d_in[3];
    const float* uew    = (const float*)d_in[4];
    const int*   fei    = (const int*)d_in[5];
    const float* few    = (const float*)d_in[6];
    const float* emb_W  = (const float*)d_in[7];
    const float* emb_b  = (const float*)d_in[8];
    const float* S_lin_W= (const float*)d_in[9];
    const float* S_lin_b= (const float*)d_in[10];
    const float* S_d    = (const float*)d_in[11];
    const float* S_hb   = (const float*)d_in[12];
    const float* S_fW   = (const float*)d_in[13];
    const float* S_fb   = (const float*)d_in[14];
    const float* F_lin_W= (const float*)d_in[15];
    const float* F_lin_b= (const float*)d_in[16];
    const float* F_d    = (const float*)d_in[17];
    const float* F_hb   = (const float*)d_in[18];
    const float* F_fW   = (const float*)d_in[19];
    const float* F_fb   = (const float*)d_in[20];
    const float* nS_w   = (const float*)d_in[21];
    const float* nS_b   = (const float*)d_in[22];
    const float* nS_m   = (const float*)d_in[23];
    const float* nF_w   = (const float*)d_in[24];
    const float* nF_b   = (const float*)d_in[25];
    const float* nF_m   = (const float*)d_in[26];
    const float* gate_W = (const float*)d_in[27];
    const float* gate_b = (const float*)d_in[28];
    float* out = (float*)d_out;

    size_t off = 0;
    auto alloc = [&](size_t bytes)->void*{
        void* p = (char*)d_ws + off;
        off += (bytes + 255) & ~(size_t)255;
        return p;
    };
    float*  xbuf   = (float*)alloc((size_t)NN * HH * 4);
    float*  hbuf   = (float*)alloc((size_t)NN * HH * 4);
    float*  fxbuf  = (float*)alloc((size_t)NN * HH * 4);
    unsigned short* xtb = (unsigned short*)alloc((size_t)NN * HH * 2);
    unsigned short* Wpb12 = (unsigned short*)alloc((size_t)12 * 32768 * 2);
    float4* pe4    = (float4*)alloc((size_t)NN * 16);
    int*    cnt    = (int*)  alloc((size_t)6 * NN * 4);
    int2*   bucket = (int2*) alloc((size_t)6 * NN * CAP * 8);
    int*    gstart = (int*)  alloc((GG + 1) * 4);
    float*  sums4  = (float*)alloc((size_t)4 * GG * HH * 4);
    float*  sumsq4 = (float*)alloc((size_t)4 * GG * HH * 4);

    const int BLK = 256;
    const int gridNH = (NN * HH) / BLK;          // 12500
    const int gridN32 = (NN + 31) / 32;          // 1563
    const int gridHop = NN / 16;                 // 3125 exact
    const int gridEdges = (2 * PP * EE + BLK - 1) / BLK;
    const int gridWb = (12 * 32768) / BLK;       // 1536

    k_bounds<<<1, 64, 0, stream>>>(batch, gstart);
    k_pe4<<<(NN + BLK - 1) / BLK, BLK, 0, stream>>>(pe, pe4);
    hipMemsetAsync(cnt, 0, (size_t)6 * NN * 4, stream);
    k_fill2<<<gridEdges, BLK, 0, stream>>>(uei, uew, fei, few, cnt, bucket);
    k_wpermb<<<gridWb, BLK, 0, stream>>>(S_fW, F_fW, Wpb12);
    k_lin64<<<gridN32, BLK, 0, stream>>>(x_in, emb_W, emb_b, xbuf);

    auto gnorm = [&](float* X, const float* w, const float* b, const float* ms){
        k_stats4<<<dim3(GG, 4), BLK, 0, stream>>>(X, gstart, sums4, sumsq4);
        k_gnorm<<<gridNH, BLK, 0, stream>>>(X, batch, gstart, sums4, sumsq4, w, b, ms);
    };

    for (int i = 0; i < LL; ++i){
        // S conv (u edges, which 0..2)
        k_lin64b<<<gridN32, BLK, 0, stream>>>(xbuf, S_lin_W + (size_t)i * HH * HH,
                                              S_lin_b + (size_t)i * HH, xtb);
        k_hop3<<<gridHop, BLK, 0, stream>>>(xtb, cnt, bucket, pe4,
                Wpb12 + (size_t)(0 * 6 + i * 3) * 32768,
                S_fb + (size_t)i * PP * HH, S_d + (size_t)i * PP * HH,
                S_hb + (size_t)i * PP * HH, hbuf);
        gnorm(hbuf, nS_w + (size_t)i * HH, nS_b + (size_t)i * HH, nS_m + (size_t)i * HH);
        // F conv (f edges, which 3..5)
        k_lin64b<<<gridN32, BLK, 0, stream>>>(hbuf, F_lin_W + (size_t)i * HH * HH,
                                              F_lin_b + (size_t)i * HH, xtb);
        k_hop3<<<gridHop, BLK, 0, stream>>>(xtb, cnt + (size_t)PP * NN,
                bucket + (size_t)PP * NN * CAP, pe4,
                Wpb12 + (size_t)(1 * 6 + i * 3) * 32768,
                F_fb + (size_t)i * PP * HH, F_d + (size_t)i * PP * HH,
                F_hb + (size_t)i * PP * HH, fxbuf);
        gnorm(fxbuf, nF_w + (size_t)i * HH, nF_b + (size_t)i * HH, nF_m + (size_t)i * HH);
        k_gate2<<<gridN32, BLK, 0, stream>>>(hbuf, fxbuf, gate_W, gate_b, xbuf);
    }

    k_stats4<<<dim3(GG, 4), BLK, 0, stream>>>(xbuf, gstart, sums4, sumsq4);
    k_finalout<<<(GG * HH + BLK - 1) / BLK, BLK, 0, stream>>>(sums4, gstart, out);
}

// Round 16
// 985.587 us; speedup vs baseline: 1.1571x; 1.1571x over previous
//
#include <hip/hip_runtime.h>
#include <cstdint>
#include <cstddef>

#define NN 50000
#define EE 300000
#define HH 64
#define PP 3
#define GG 50
#define LL 2
#define CAP 32
#define SLOPE 0.01f

typedef __attribute__((ext_vector_type(8))) short bf16x8;
typedef __attribute__((ext_vector_type(4))) float f32x4;

__device__ __forceinline__ float lrelu(float x){ return x >= 0.f ? x : SLOPE*x; }

__device__ __forceinline__ unsigned short f2bf(float x){
    uint32_t u = __float_as_uint(x);
    uint32_t r = (u + 0x7FFFu + ((u >> 16) & 1u)) >> 16;
    return (unsigned short)r;
}
__device__ __forceinline__ float bf2f(unsigned short s){
    return __uint_as_float((uint32_t)s << 16);
}

// gstart[g] = first index i with batch[i] >= g (batch sorted); gstart[GG] = NN
__global__ void k_bounds(const int* __restrict__ batch, int* __restrict__ gstart){
    int g = threadIdx.x;
    if (g > GG) return;
    int lo = 0, hi = NN;
    while (lo < hi){ int mid = (lo + hi) >> 1; if (batch[mid] < g) lo = mid + 1; else hi = mid; }
    gstart[g] = lo;
}

// pe4[n] = {pe[n][0], pe[n][1], pe[n][2], 0}
__global__ void k_pe4(const float* __restrict__ pe, float4* __restrict__ pe4){
    int n = blockIdx.x * blockDim.x + threadIdx.x;
    if (n >= NN) return;
    pe4[n] = make_float4(pe[n * 3 + 0], pe[n * 3 + 1], pe[n * 3 + 2], 0.f);
}

// Single-pass bucket-CSR fill over all 6 edge sets.
__global__ void k_fill2(const int* __restrict__ uei, const float* __restrict__ uew,
                        const int* __restrict__ fei, const float* __restrict__ few,
                        int* __restrict__ cnt, int2* __restrict__ bucket){
    int t = blockIdx.x * blockDim.x + threadIdx.x;
    if (t >= 2 * PP * EE) return;
    int which = t / EE;
    int e = t - which * EE;
    const int* ei; const float* ew; int p;
    if (which < PP){ ei = uei; ew = uew; p = which; }
    else           { ei = fei; ew = few; p = which - PP; }
    int row = ei[(size_t)(p * 2 + 0) * EE + e];
    int col = ei[(size_t)(p * 2 + 1) * EE + e];
    float w = ew[(size_t)p * EE + e];
    int slot = atomicAdd(cnt + (size_t)which * NN + row, 1);
    if (slot < CAP)
        bucket[((size_t)which * NN + row) * CAP + slot] = make_int2(col, __float_as_int(w));
}

// Pre-pack ALL 12 fusion weight matrices into bf16 B-fragment order.
__global__ void k_wpermb(const float* __restrict__ S_fW, const float* __restrict__ F_fW,
                         unsigned short* __restrict__ Wpb){
    int gid = blockIdx.x * blockDim.x + threadIdx.x;   // 12*16*4*64*8 = 393216
    int j = gid & 7;
    int lane = (gid >> 3) & 63;
    int w = (gid >> 9) & 3;
    int kb = (gid >> 11) & 15;
    int t = gid >> 15;
    int q = kb * 32 + (lane >> 4) * 8 + j;
    int col = w * 16 + (lane & 15);
    int conv = t / 6, layer = (t % 6) / 3, p = t % 3;
    const float* src = (conv ? F_fW : S_fW) + ((size_t)layer * PP + p) * 512 * HH;
    int kref;
    if (q < 128) kref = q;
    else { int r = q - 128; kref = 128 + (r & 63) * 6 + (r >> 6); }
    Wpb[gid] = f2bf(src[(size_t)kref * HH + col]);
}

// Register-blocked (N,64)@(64,64), fp32 out.
__global__ __launch_bounds__(256) void k_lin64(const float* __restrict__ X,
                       const float* __restrict__ W, const float* __restrict__ b,
                       float* __restrict__ out){
    __shared__ float xs[32][HH];
    int nb = blockIdx.x * 32;
    int t = threadIdx.x;
    #pragma unroll
    for (int i = 0; i < 2; ++i){
        int idx = t + 256 * i;
        int r = idx >> 4, c4 = idx & 15;
        int n = nb + r;
        float4 v = make_float4(0.f, 0.f, 0.f, 0.f);
        if (n < NN) v = *reinterpret_cast<const float4*>(X + (size_t)n * HH + c4 * 4);
        *reinterpret_cast<float4*>(&xs[r][c4 * 4]) = v;
    }
    __syncthreads();
    int lane = t & 63, wave = t >> 6, nw = wave * 8;
    float acc[8];
    float bb = b[lane];
    #pragma unroll
    for (int i = 0; i < 8; ++i) acc[i] = bb;
    #pragma unroll 2
    for (int k = 0; k < HH; ++k){
        float wv = W[(size_t)k * HH + lane];
        #pragma unroll
        for (int i = 0; i < 8; ++i) acc[i] += xs[nw + i][k] * wv;
    }
    #pragma unroll
    for (int i = 0; i < 8; ++i){
        int n = nb + nw + i;
        if (n < NN) out[(size_t)n * HH + lane] = acc[i];
    }
}

// bf16-out linear (raw input), for S-conv xt.
__global__ __launch_bounds__(256) void k_lin64b(const float* __restrict__ X,
                       const float* __restrict__ W, const float* __restrict__ b,
                       unsigned short* __restrict__ out){
    __shared__ float xs[32][HH];
    int nb = blockIdx.x * 32;
    int t = threadIdx.x;
    #pragma unroll
    for (int i = 0; i < 2; ++i){
        int idx = t + 256 * i;
        int r = idx >> 4, c4 = idx & 15;
        int n = nb + r;
        float4 v = make_float4(0.f, 0.f, 0.f, 0.f);
        if (n < NN) v = *reinterpret_cast<const float4*>(X + (size_t)n * HH + c4 * 4);
        *reinterpret_cast<float4*>(&xs[r][c4 * 4]) = v;
    }
    __syncthreads();
    int lane = t & 63, wave = t >> 6, nw = wave * 8;
    float acc[8];
    float bb = b[lane];
    #pragma unroll
    for (int i = 0; i < 8; ++i) acc[i] = bb;
    #pragma unroll 2
    for (int k = 0; k < HH; ++k){
        float wv = W[(size_t)k * HH + lane];
        #pragma unroll
        for (int i = 0; i < 8; ++i) acc[i] += xs[nw + i][k] * wv;
    }
    #pragma unroll
    for (int i = 0; i < 8; ++i){
        int n = nb + nw + i;
        if (n < NN) out[(size_t)n * HH + lane] = f2bf(acc[i]);
    }
}

// bf16-out linear with fused graph-norm+lrelu on the INPUT:
// in_eff[n][o] = lrelu(X[n][o]*scale[g][o] + shift[g][o]),  g = batch[n]
__global__ __launch_bounds__(256) void k_lin64bg(const float* __restrict__ X,
                       const int* __restrict__ batch,
                       const float* __restrict__ scale, const float* __restrict__ shift,
                       const float* __restrict__ W, const float* __restrict__ b,
                       unsigned short* __restrict__ out){
    __shared__ float xs[32][HH];
    int nb = blockIdx.x * 32;
    int t = threadIdx.x;
    #pragma unroll
    for (int i = 0; i < 2; ++i){
        int idx = t + 256 * i;
        int r = idx >> 4, c4 = idx & 15;
        int n = nb + r;
        if (n < NN){
            int g = batch[n];
            float4 v = *reinterpret_cast<const float4*>(X + (size_t)n * HH + c4 * 4);
            float4 sc = *reinterpret_cast<const float4*>(scale + (size_t)g * HH + c4 * 4);
            float4 sh = *reinterpret_cast<const float4*>(shift + (size_t)g * HH + c4 * 4);
            v.x = lrelu(v.x * sc.x + sh.x);
            v.y = lrelu(v.y * sc.y + sh.y);
            v.z = lrelu(v.z * sc.z + sh.z);
            v.w = lrelu(v.w * sc.w + sh.w);
            *reinterpret_cast<float4*>(&xs[r][c4 * 4]) = v;
        } else {
            *reinterpret_cast<float4*>(&xs[r][c4 * 4]) = make_float4(0.f,0.f,0.f,0.f);
        }
    }
    __syncthreads();
    int lane = t & 63, wave = t >> 6, nw = wave * 8;
    float acc[8];
    float bb = b[lane];
    #pragma unroll
    for (int i = 0; i < 8; ++i) acc[i] = bb;
    #pragma unroll 2
    for (int k = 0; k < HH; ++k){
        float wv = W[(size_t)k * HH + lane];
        #pragma unroll
        for (int i = 0; i < 8; ++i) acc[i] += xs[nw + i][k] * wv;
    }
    #pragma unroll
    for (int i = 0; i < 8; ++i){
        int n = nb + nw + i;
        if (n < NN) out[(size_t)n * HH + lane] = f2bf(acc[i]);
    }
}

// Whole OPDMP (3 hops), MFMA phase B, bf16 xt gathers.  (round-14 proven version)
__global__ __launch_bounds__(256) void k_hop3(const unsigned short* __restrict__ xtb,
        const int* __restrict__ cnt, const int2* __restrict__ bucket,
        const float4* __restrict__ pe4, const unsigned short* __restrict__ Wpb3,
        const float* __restrict__ fb3, const float* __restrict__ dmat,
        const float* __restrict__ hb3, float* __restrict__ outb){
    __shared__ unsigned short u[16][512];
    int nb = blockIdx.x * 16;
    int t = threadIdx.x;
    int lane = t & 63, wave = t >> 6, nw = wave * 4;
    {
        int r = t >> 4, c4 = t & 15;
        ushort4 s = *reinterpret_cast<const ushort4*>(xtb + (size_t)(nb + r) * HH + c4 * 4);
        int q = (c4 * 4) ^ ((r & 7) << 3);
        *reinterpret_cast<ushort4*>(&u[r][q]) = s;
    }
    int c = wave * 16 + (lane & 15);
    float d0 = dmat[c], d1 = dmat[64 + c], d2 = dmat[128 + c];
    float mx = fmaxf(d0, fmaxf(d1, d2));
    float e0 = expf(d0 - mx), e1 = expf(d1 - mx), e2 = expf(d2 - mx);
    float esum = e0 + e1 + e2;
    float dw0 = e0 / esum, dw1 = e1 / esum, dw2 = e2 / esum;
    float accOut[4];
    float hbs = hb3[c] + hb3[64 + c] + hb3[128 + c];
    #pragma unroll
    for (int r = 0; r < 4; ++r) accOut[r] = hbs;

    for (int p = 0; p < 3; ++p){
        __syncthreads();
        const int*  cntp = cnt + (size_t)p * NN;
        const int2* bp   = bucket + (size_t)p * NN * CAP;
        #pragma unroll
        for (int i = 0; i < 4; ++i){
            int n = nb + nw + i;
            float accA = 0.f, sumw = 0.f;
            float a0 = 0.f, a1 = 0.f, a2 = 0.f, a3 = 0.f, a4 = 0.f, a5 = 0.f;
            int len = cntp[n]; if (len > CAP) len = CAP;
            const int2* b = bp + (size_t)n * CAP;
            float4 pr = pe4[n];
            {   // predicated batch covering s=0..7
                int  cols[8]; float ws[8];
                #pragma unroll
                for (int s = 0; s < 8; ++s){
                    int2 m = b[s];
                    bool ok = (s < len);
                    cols[s] = ok ? m.x : n;
                    ws[s]   = ok ? __int_as_float(m.y) : 0.f;
                }
                float4 pcs[8]; float xvs[8];
                #pragma unroll
                for (int s = 0; s < 8; ++s){
                    pcs[s] = pe4[cols[s]];
                    xvs[s] = bf2f(xtb[(size_t)cols[s] * HH + lane]);
                }
                #pragma unroll
                for (int s = 0; s < 8; ++s){
                    float w = ws[s], xv = xvs[s];
                    float dd0 = pcs[s].x - pr.x;
                    float dd1 = pcs[s].y - pr.y;
                    float dd2 = pcs[s].z - pr.z;
                    sumw += w;  accA += w * xv;
                    a0 += fmaxf(dd0, 0.f) * xv;  a3 += fmaxf(-dd0, 0.f) * xv;
                    a1 += fmaxf(dd1, 0.f) * xv;  a4 += fmaxf(-dd1, 0.f) * xv;
                    a2 += fmaxf(dd2, 0.f) * xv;  a5 += fmaxf(-dd2, 0.f) * xv;
                }
            }
            if (len > 8){   // predicated batch covering s=8..15
                int  cols[8]; float ws[8];
                #pragma unroll
                for (int s = 0; s < 8; ++s){
                    int2 m = b[8 + s];
                    bool ok = (8 + s < len);
                    cols[s] = ok ? m.x : n;
                    ws[s]   = ok ? __int_as_float(m.y) : 0.f;
                }
                float4 pcs[8]; float xvs[8];
                #pragma unroll
                for (int s = 0; s < 8; ++s){
                    pcs[s] = pe4[cols[s]];
                    xvs[s] = bf2f(xtb[(size_t)cols[s] * HH + lane]);
                }
                #pragma unroll
                for (int s = 0; s < 8; ++s){
                    float w = ws[s], xv = xvs[s];
                    float dd0 = pcs[s].x - pr.x;
                    float dd1 = pcs[s].y - pr.y;
                    float dd2 = pcs[s].z - pr.z;
                    sumw += w;  accA += w * xv;
                    a0 += fmaxf(dd0, 0.f) * xv;  a3 += fmaxf(-dd0, 0.f) * xv;
                    a1 += fmaxf(dd1, 0.f) * xv;  a4 += fmaxf(-dd1, 0.f) * xv;
                    a2 += fmaxf(dd2, 0.f) * xv;  a5 += fmaxf(-dd2, 0.f) * xv;
                }
            }
            for (int s = 16; s < len; ++s){      // P(len>16) ~ 2e-4
                int2 m = b[s];
                int col = m.x;
                float w = __int_as_float(m.y);
                float4 pc = pe4[col];
                float xv = bf2f(xtb[(size_t)col * HH + lane]);
                float dd0 = pc.x - pr.x;
                float dd1 = pc.y - pr.y;
                float dd2 = pc.z - pr.z;
                sumw += w;  accA += w * xv;
                a0 += fmaxf(dd0, 0.f) * xv;  a3 += fmaxf(-dd0, 0.f) * xv;
                a1 += fmaxf(dd1, 0.f) * xv;  a4 += fmaxf(-dd1, 0.f) * xv;
                a2 += fmaxf(dd2, 0.f) * xv;  a5 += fmaxf(-dd2, 0.f) * xv;
            }
            float di = (sumw == 0.f) ? 0.f : 1.f / sumw;
            int il = nw + i;
            int sw = (il & 7) << 3;
            u[il][(64 + lane) ^ sw]           = f2bf(accA * di);
            u[il][(128 + 0 * 64 + lane) ^ sw] = f2bf(a0 * di);
            u[il][(128 + 1 * 64 + lane) ^ sw] = f2bf(a1 * di);
            u[il][(128 + 2 * 64 + lane) ^ sw] = f2bf(a2 * di);
            u[il][(128 + 3 * 64 + lane) ^ sw] = f2bf(a3 * di);
            u[il][(128 + 4 * 64 + lane) ^ sw] = f2bf(a4 * di);
            u[il][(128 + 5 * 64 + lane) ^ sw] = f2bf(a5 * di);
        }
        __syncthreads();
        const unsigned short* wb = Wpb3 + (size_t)p * 32768;
        f32x4 acc = {0.f, 0.f, 0.f, 0.f};
        int arow = lane & 15;
        int asw = (arow & 7) << 3;
        #pragma unroll
        for (int kb = 0; kb < 16; ++kb){
            int qa = (kb * 32 + (lane >> 4) * 8) ^ asw;
            bf16x8 a = *reinterpret_cast<const bf16x8*>(&u[arow][qa]);
            bf16x8 b = *reinterpret_cast<const bf16x8*>(&wb[(((size_t)kb * 4 + wave) * 64 + lane) * 8]);
            acc = __builtin_amdgcn_mfma_f32_16x16x32_bf16(a, b, acc, 0, 0, 0);
        }
        float fbv = fb3[p * 64 + c];
        float dw = (p == 0) ? dw0 : ((p == 1) ? dw1 : dw2);
        #pragma unroll
        for (int r = 0; r < 4; ++r)
            accOut[r] += lrelu(acc[r] + fbv) * dw;
    }
    #pragma unroll
    for (int r = 0; r < 4; ++r){
        int row = (lane >> 4) * 4 + r;
        outb[(size_t)(nb + row) * HH + c] = accOut[r];
    }
}

// Per-graph partial sums/sumsq in 4 row-chunks (no atomics, no memset).
__global__ void k_stats4(const float* __restrict__ X, const int* __restrict__ gstart,
                         float* __restrict__ sums4, float* __restrict__ sumsq4){
    int g = blockIdx.x, chunk = blockIdx.y;
    int o = threadIdx.x & 63, sub = threadIdx.x >> 6;
    int ns = gstart[g], ne = gstart[g + 1];
    float s = 0.f, q = 0.f;
    for (int n = ns + chunk * 4 + sub; n < ne; n += 16){
        float v = X[(size_t)n * 64 + o];
        s += v; q += v * v;
    }
    __shared__ float ls[4][64];
    __shared__ float lq[4][64];
    ls[sub][o] = s; lq[sub][o] = q;
    __syncthreads();
    if (sub == 0){
        #pragma unroll
        for (int k = 1; k < 4; ++k){ s += ls[k][o]; q += lq[k][o]; }
        sums4 [(size_t)(chunk * GG + g) * 64 + o] = s;
        sumsq4[(size_t)(chunk * GG + g) * 64 + o] = q;
    }
}

// Fold stats into per-(g,o) affine: scale = w/sqrt(var+eps), shift = b - mean*ms*scale
__global__ void k_prep(const int* __restrict__ gstart,
                       const float* __restrict__ sums4, const float* __restrict__ sumsq4,
                       const float* __restrict__ w, const float* __restrict__ b,
                       const float* __restrict__ ms,
                       float* __restrict__ scale, float* __restrict__ shift){
    int g = blockIdx.x, o = threadIdx.x;
    float cnt = fmaxf((float)(gstart[g + 1] - gstart[g]), 1.f);
    float sm = 0.f, sq = 0.f;
    #pragma unroll
    for (int cC = 0; cC < 4; ++cC){
        sm += sums4 [(size_t)(cC * GG + g) * 64 + o];
        sq += sumsq4[(size_t)(cC * GG + g) * 64 + o];
    }
    float mean = sm / cnt;
    float ex2 = sq / cnt;
    float m = ms[o];
    float var = ex2 - mean * mean * m * (2.f - m);
    float sc = (1.f / sqrtf(var + 1e-5f)) * w[o];
    scale[g * HH + o] = sc;
    shift[g * HH + o] = b[o] - mean * m * sc;
}

// Gate with fused graph-norm+lrelu on both inputs:
// hN = lrelu(h*scS+shS), fN = lrelu(fx*scF+shF); gate = sigmoid([hN,fN]@gW+gb);
// X += gate*hN + (1-gate)*fN
__global__ __launch_bounds__(256) void k_gate2g(const float* __restrict__ h,
                       const float* __restrict__ fx, const int* __restrict__ batch,
                       const float* __restrict__ scS, const float* __restrict__ shS,
                       const float* __restrict__ scF, const float* __restrict__ shF,
                       const float* __restrict__ gW, const float* __restrict__ gb,
                       float* __restrict__ X){
    __shared__ float hs[32][HH];
    __shared__ float fs[32][HH];
    int nb = blockIdx.x * 32;
    int t = threadIdx.x;
    #pragma unroll
    for (int i = 0; i < 2; ++i){
        int idx = t + 256 * i;
        int r = idx >> 4, c4 = idx & 15;
        int n = nb + r;
        if (n < NN){
            int g = batch[n];
            float4 vh = *reinterpret_cast<const float4*>(h  + (size_t)n * HH + c4 * 4);
            float4 vf = *reinterpret_cast<const float4*>(fx + (size_t)n * HH + c4 * 4);
            float4 s1 = *reinterpret_cast<const float4*>(scS + (size_t)g * HH + c4 * 4);
            float4 h1 = *reinterpret_cast<const float4*>(shS + (size_t)g * HH + c4 * 4);
            float4 s2 = *reinterpret_cast<const float4*>(scF + (size_t)g * HH + c4 * 4);
            float4 h2 = *reinterpret_cast<const float4*>(shF + (size_t)g * HH + c4 * 4);
            vh.x = lrelu(vh.x * s1.x + h1.x); vh.y = lrelu(vh.y * s1.y + h1.y);
            vh.z = lrelu(vh.z * s1.z + h1.z); vh.w = lrelu(vh.w * s1.w + h1.w);
            vf.x = lrelu(vf.x * s2.x + h2.x); vf.y = lrelu(vf.y * s2.y + h2.y);
            vf.z = lrelu(vf.z * s2.z + h2.z); vf.w = lrelu(vf.w * s2.w + h2.w);
            *reinterpret_cast<float4*>(&hs[r][c4 * 4]) = vh;
            *reinterpret_cast<float4*>(&fs[r][c4 * 4]) = vf;
        } else {
            *reinterpret_cast<float4*>(&hs[r][c4 * 4]) = make_float4(0.f,0.f,0.f,0.f);
            *reinterpret_cast<float4*>(&fs[r][c4 * 4]) = make_float4(0.f,0.f,0.f,0.f);
        }
    }
    __syncthreads();
    int lane = t & 63, wave = t >> 6, nw = wave * 8;
    float acc[8];
    float bb = gb[lane];
    #pragma unroll
    for (int i = 0; i < 8; ++i) acc[i] = bb;
    #pragma unroll 2
    for (int k = 0; k < HH; ++k){
        float w1 = gW[(size_t)k * HH + lane];
        float w2 = gW[(size_t)(64 + k) * HH + lane];
        #pragma unroll
        for (int i = 0; i < 8; ++i) acc[i] += hs[nw + i][k] * w1 + fs[nw + i][k] * w2;
    }
    #pragma unroll
    for (int i = 0; i < 8; ++i){
        int n = nb + nw + i;
        if (n < NN){
            float gt = 1.f / (1.f + expf(-acc[i]));
            float hv = hs[nw + i][lane];
            float fv = fs[nw + i][lane];
            size_t idx = (size_t)n * HH + lane;
            X[idx] = gt * hv + (1.f - gt) * fv + X[idx];
        }
    }
}

__global__ void k_finalout(const float* __restrict__ sums4, const int* __restrict__ gstart,
                           float* __restrict__ out){
    int gid = blockIdx.x * blockDim.x + threadIdx.x;
    if (gid >= GG * HH) return;
    int g = gid >> 6, o = gid & 63;
    float cnt = fmaxf((float)(gstart[g + 1] - gstart[g]), 1.f);
    float sm = 0.f;
    #pragma unroll
    for (int cC = 0; cC < 4; ++cC) sm += sums4[(size_t)(cC * GG + g) * 64 + o];
    out[gid] = sm / cnt;
}

extern "C" void kernel_launch(void* const* d_in, const int* in_sizes, int n_in,
                              void* d_out, int out_size, void* d_ws, size_t ws_size,
                              hipStream_t stream) {
    const float* x_in   = (const float*)d_in[0];
    const float* pe     = (const float*)d_in[1];
    const int*   batch  = (const int*)d_in[2];
    const int*   uei    = (const int*)d_in[3];
    const float* uew    = (const float*)d_in[4];
    const int*   fei    = (const int*)d_in[5];
    const float* few    = (const float*)d_in[6];
    const float* emb_W  = (const float*)d_in[7];
    const float* emb_b  = (const float*)d_in[8];
    const float* S_lin_W= (const float*)d_in[9];
    const float* S_lin_b= (const float*)d_in[10];
    const float* S_d    = (const float*)d_in[11];
    const float* S_hb   = (const float*)d_in[12];
    const float* S_fW   = (const float*)d_in[13];
    const float* S_fb   = (const float*)d_in[14];
    const float* F_lin_W= (const float*)d_in[15];
    const float* F_lin_b= (const float*)d_in[16];
    const float* F_d    = (const float*)d_in[17];
    const float* F_hb   = (const float*)d_in[18];
    const float* F_fW   = (const float*)d_in[19];
    const float* F_fb   = (const float*)d_in[20];
    const float* nS_w   = (const float*)d_in[21];
    const float* nS_b   = (const float*)d_in[22];
    const float* nS_m   = (const float*)d_in[23];
    const float* nF_w   = (const float*)d_in[24];
    const float* nF_b   = (const float*)d_in[25];
    const float* nF_m   = (const float*)d_in[26];
    const float* gate_W = (const float*)d_in[27];
    const float* gate_b = (const float*)d_in[28];
    float* out = (float*)d_out;

    size_t off = 0;
    auto alloc = [&](size_t bytes)->void*{
        void* p = (char*)d_ws + off;
        off += (bytes + 255) & ~(size_t)255;
        return p;
    };
    float*  xbuf   = (float*)alloc((size_t)NN * HH * 4);
    float*  hbuf   = (float*)alloc((size_t)NN * HH * 4);
    float*  fxbuf  = (float*)alloc((size_t)NN * HH * 4);
    unsigned short* xtb = (unsigned short*)alloc((size_t)NN * HH * 2);
    unsigned short* Wpb12 = (unsigned short*)alloc((size_t)12 * 32768 * 2);
    float4* pe4    = (float4*)alloc((size_t)NN * 16);
    int*    cnt    = (int*)  alloc((size_t)6 * NN * 4);
    int2*   bucket = (int2*) alloc((size_t)6 * NN * CAP * 8);
    int*    gstart = (int*)  alloc((GG + 1) * 4);
    float*  sums4  = (float*)alloc((size_t)4 * GG * HH * 4);
    float*  sumsq4 = (float*)alloc((size_t)4 * GG * HH * 4);
    float*  scS    = (float*)alloc(GG * HH * 4);
    float*  shS    = (float*)alloc(GG * HH * 4);
    float*  scF    = (float*)alloc(GG * HH * 4);
    float*  shF    = (float*)alloc(GG * HH * 4);

    const int BLK = 256;
    const int gridN32 = (NN + 31) / 32;          // 1563
    const int gridHop = NN / 16;                 // 3125 exact
    const int gridEdges = (2 * PP * EE + BLK - 1) / BLK;
    const int gridWb = (12 * 32768) / BLK;       // 1536

    k_bounds<<<1, 64, 0, stream>>>(batch, gstart);
    k_pe4<<<(NN + BLK - 1) / BLK, BLK, 0, stream>>>(pe, pe4);
    hipMemsetAsync(cnt, 0, (size_t)6 * NN * 4, stream);
    k_fill2<<<gridEdges, BLK, 0, stream>>>(uei, uew, fei, few, cnt, bucket);
    k_wpermb<<<gridWb, BLK, 0, stream>>>(S_fW, F_fW, Wpb12);
    k_lin64<<<gridN32, BLK, 0, stream>>>(x_in, emb_W, emb_b, xbuf);

    for (int i = 0; i < LL; ++i){
        // S conv (u edges)
        k_lin64b<<<gridN32, BLK, 0, stream>>>(xbuf, S_lin_W + (size_t)i * HH * HH,
                                              S_lin_b + (size_t)i * HH, xtb);
        k_hop3<<<gridHop, BLK, 0, stream>>>(xtb, cnt, bucket, pe4,
                Wpb12 + (size_t)(0 * 6 + i * 3) * 32768,
                S_fb + (size_t)i * PP * HH, S_d + (size_t)i * PP * HH,
                S_hb + (size_t)i * PP * HH, hbuf);
        k_stats4<<<dim3(GG, 4), BLK, 0, stream>>>(hbuf, gstart, sums4, sumsq4);
        k_prep<<<GG, 64, 0, stream>>>(gstart, sums4, sumsq4,
                nS_w + (size_t)i * HH, nS_b + (size_t)i * HH, nS_m + (size_t)i * HH,
                scS, shS);
        // F conv (f edges), input = gnorm+lrelu(hbuf) fused into staging
        k_lin64bg<<<gridN32, BLK, 0, stream>>>(hbuf, batch, scS, shS,
                                               F_lin_W + (size_t)i * HH * HH,
                                               F_lin_b + (size_t)i * HH, xtb);
        k_hop3<<<gridHop, BLK, 0, stream>>>(xtb, cnt + (size_t)PP * NN,
                bucket + (size_t)PP * NN * CAP, pe4,
                Wpb12 + (size_t)(1 * 6 + i * 3) * 32768,
                F_fb + (size_t)i * PP * HH, F_d + (size_t)i * PP * HH,
                F_hb + (size_t)i * PP * HH, fxbuf);
        k_stats4<<<dim3(GG, 4), BLK, 0, stream>>>(fxbuf, gstart, sums4, sumsq4);
        k_prep<<<GG, 64, 0, stream>>>(gstart, sums4, sumsq4,
                nF_w + (size_t)i * HH, nF_b + (size_t)i * HH, nF_m + (size_t)i * HH,
                scF, shF);
        k_gate2g<<<gridN32, BLK, 0, stream>>>(hbuf, fxbuf, batch, scS, shS, scF, shF,
                                              gate_W, gate_b, xbuf);
    }

    k_stats4<<<dim3(GG, 4), BLK, 0, stream>>>(xbuf, gstart, sums4, sumsq4);
    k_finalout<<<(GG * HH + BLK - 1) / BLK, BLK, 0, stream>>>(sums4, gstart, out);
}